// Round 11
// baseline (264.692 us; speedup 1.0000x reference)
//
#include <hip/hip_runtime.h>
#include <cstdint>
#include <cstddef>
#include <math.h>

#define BATCH 8192

typedef unsigned long long u64;
typedef uint32_t u32;
typedef int v4i __attribute__((ext_vector_type(4)));
typedef int v16i __attribute__((ext_vector_type(16)));
typedef float f32x2 __attribute__((ext_vector_type(2)));

// ---- f64 BN semantics (matching the float64 numpy reference; R5-verified absmax=0) ----
__device__ __forceinline__ double bn_inv_d(float g, float v) {
    return (double)g * (1.0 / sqrt((double)v + 1e-5));
}
__device__ __forceinline__ double bn_shift_d(float be, float m, double iv) {
    return (double)be - (double)m * iv;
}
__device__ __forceinline__ double bn_eval_d(double conv, double B, double iv, double sh) {
    return (conv + B) * iv + sh;
}

// y(p) weakly decreasing => binary search == linear scan, bit-identical (R8/R9-verified).
template <typename F>
__device__ __forceinline__ int max_p_nonneg(F y, int maxp) {
    if (!(y(0) >= 0.0)) return -1;
    if (y(maxp) >= 0.0) return maxp;
    int lo = 0, hi = maxp;
    while (hi - lo > 1) {
        int mid = (lo + hi) >> 1;
        if (y(mid) >= 0.0) lo = mid; else hi = mid;
    }
    return lo;
}

// ---------------- one merged prep kernel (R9-verified) ----------------
__global__ __launch_bounds__(256) void prep_all(
    const float* w1, const float* b1, const float* w2, const float* b2,
    const float* w3, const float* b3, const float* w4, const float* b4,
    const float* wf,
    const float* g1, const float* be1, const float* m1, const float* v1,
    const float* g2, const float* be2, const float* m2, const float* v2,
    const float* g3, const float* be3, const float* m3, const float* v3,
    const float* g4, const float* be4, const float* m4, const float* v4,
    float* s1f, double* T1, u32* wt2w, int* T2,
    uint4* b3i8, int* C3, u64* wt4, int* T4, u64* wtf) {
    int t = blockIdx.x * 256 + threadIdx.x;

    if (t < 384) {
        int co = t / 12, k = t % 12;
        float val = 0.f;
        if (k < 9) {
            double iv = bn_inv_d(g1[co], v1[co]);
            float d = (iv < 0.0) ? -1.f : 1.f;
            val = ((w1[co * 9 + k] >= 0.f) ? 1.f : -1.f) * d;
        }
        s1f[t] = val;
    } else if (t < 416) {
        int co = t - 384;
        double iv = bn_inv_d(g1[co], v1[co]);
        double sh = bn_shift_d(be1[co], m1[co], iv);
        double B = (double)b1[co];
        bool flip = (iv < 0.0);
        double tt = -sh / iv - B;
        T1[co] = flip ? -tt : tt;
    } else if (t < 608) {
        int idx = t - 416;
        int co = idx / 3, kw = idx % 3;
        double iv = bn_inv_d(g2[co], v2[co]);
        bool flip = (iv < 0.0);
        u32 wb = 0;
        for (int ci = 0; ci < 32; ++ci)
            wb |= (u32)((w2[(co * 32 + ci) * 3 + kw] >= 0.f) != flip) << ci;
        wt2w[co * 4 + kw] = wb;
    } else if (t < 800) {
        int idx = t - 608;
        int co = idx & 63, cls = idx >> 6;
        double iv = bn_inv_d(g2[co], v2[co]);
        double sh = bn_shift_d(be2[co], m2[co], iv);
        double B = (double)b2[co];
        bool flip = (iv < 0.0);
        int spur = 0, nv = 3;
        if (cls == 1) { nv = 2; for (int ci = 0; ci < 32; ++ci) spur += (int)((w2[(co * 32 + ci) * 3 + 0] >= 0.f) != flip); }
        if (cls == 2) { nv = 2; for (int ci = 0; ci < 32; ++ci) spur += (int)((w2[(co * 32 + ci) * 3 + 2] >= 0.f) != flip); }
        int maxp = 32 * nv + spur;
        auto y = [&](int p) {
            int conv = flip ? (2 * (p - spur) - 32 * nv) : (32 * nv - 2 * (p - spur));
            return bn_eval_d((double)conv, B, iv, sh);
        };
        T2[cls * 64 + co] = max_p_nonneg(y, maxp);
    } else if (t < 2336) {
        int idx = t - 800;
        int q = idx >> 7, n = idx & 127;
        double iv = bn_inv_d(g3[n], v3[n]);
        bool flip = (iv < 0.0);
        int kw = q >> 2, ci0 = (q & 3) * 16;
        u32 wd[4] = {0, 0, 0, 0};
        for (int j = 0; j < 16; ++j) {
            int ci = ci0 + j;
            bool pos = (w3[(n * 64 + ci) * 3 + kw] >= 0.f) != flip;
            u32 byte = pos ? 0x01u : 0xFFu;
            wd[j >> 2] |= byte << (8 * (j & 3));
        }
        b3i8[idx] = make_uint4(wd[0], wd[1], wd[2], wd[3]);
    } else if (t < 2464) {
        int co = t - 2336;
        double iv = bn_inv_d(g3[co], v3[co]);
        double sh = bn_shift_d(be3[co], m3[co], iv);
        double B = (double)b3[co];
        auto y = [&](int v) { return bn_eval_d((double)v, B, iv, sh); };
        int C = 1000;
        if (iv >= 0.0) {
            if (y(192) >= 0.0) {
                if (y(-192) >= 0.0) C = -192;
                else {
                    int lo = 0, hi = 192;
                    while (hi - lo > 1) {
                        int mid = (lo + hi) >> 1;
                        if (y(-192 + 2 * mid) >= 0.0) hi = mid; else lo = mid;
                    }
                    C = -192 + 2 * hi;
                }
            }
        } else {
            if (y(192) >= 0.0) C = -192;
            else if (y(-192) >= 0.0) {
                int lo = 0, hi = 192;
                while (hi - lo > 1) {
                    int mid = (lo + hi) >> 1;
                    if (y(-192 + 2 * mid) >= 0.0) lo = mid; else hi = mid;
                }
                C = -(-192 + 2 * lo);
            }
        }
        C3[co] = C;
    } else if (t < 4000) {
        int idx = t - 2464;
        int j = idx & 1, ch = idx >> 1;
        int co = ch / 6, h = ch % 6;
        double iv = bn_inv_d(g4[co], v4[co]);
        bool flip = (iv < 0.0);
        u64 wb = 0;
        for (int cb = 0; cb < 64; ++cb) {
            int ci = j * 64 + cb;
            wb |= (u64)((w4[(co * 128 + ci) * 6 + h] >= 0.f) != flip) << cb;
        }
        wt4[idx] = wb;
    } else if (t < 4128) {
        int co = t - 4000;
        double iv = bn_inv_d(g4[co], v4[co]);
        double sh = bn_shift_d(be4[co], m4[co], iv);
        double B = (double)b4[co];
        bool flip = (iv < 0.0);
        auto y = [&](int p) {
            int conv = flip ? (2 * p - 768) : (768 - 2 * p);
            return bn_eval_d((double)conv, B, iv, sh);
        };
        T4[co] = max_p_nonneg(y, 768);
    } else if (t < 4448) {
        int idx = t - 4128;
        int o = idx / 32, wi = idx % 32;
        u64 wb = 0;
        for (int fb = 0; fb < 64; ++fb)
            wb |= (u64)(wf[o * 2048 + wi * 64 + fb] >= 0.f) << fb;
        wtf[idx] = wb;
    }
}

// ---------------- fully-fused L1..L4+FC (R10-verified structure; L1 packed-f32) ----------------
// LDS staging of B3/W4/Wf is LOAD-BEARING (R8: un-staging -> 557MB HBM fetch, 285us).
// 42368 B; 128KiB/CU co-residency pool / 42368 -> 3 blocks/CU (same as R10). VALU-bound ~90%.
// L1 input re-staged as packed pairs sXP[j] = (xpad[j], xpad[j+2]) so the two pooled
// conv outputs compute as ONE v_pk_fma_f32 chain (9 packed FMA vs 18 scalar).
// smem layout:
//   [0,24576)     sB3                        -> after L3: sW4 [0,12288) + sWf [12288,14848)
//   [24576,24704) sLUT4 (2x16 u32)
//   [24704,24960) sC3 short[128]
//   [24960,25984) sW2 uint4[64]              -> after L3: sFeat u64[4][32]
//   [25984,26368) sT2 short[192]             -> after L3: sT4 short[128] + sBf f32[10]
//   [26368,42368) union{ sXP f32x2[8][138] @26368 (8832) + sA1 u32[8][32] @35200 | sA3 @26368 (6144) } + sA2 @36224 (6144)
#define RB 24
__global__ __launch_bounds__(256, 3) void mega_kernel(
    const float* __restrict__ x, const float4* __restrict__ s1p, const double* __restrict__ T1g,
    const uint4* __restrict__ wt2v, const int* __restrict__ T2g,
    const uint4* __restrict__ b3i8, const int* __restrict__ C3g,
    const u64* __restrict__ wt4, const int* __restrict__ T4g,
    const u64* __restrict__ wtf, const float* __restrict__ bfg,
    float* __restrict__ out) {
    __shared__ __attribute__((aligned(16))) char smem[42368];
    uint4* sB3  = (uint4*)smem;
    u32*  sLUT4 = (u32*)(smem + 24576);     // [2][16]
    short* sC3  = (short*)(smem + 24704);
    uint4* sW2  = (uint4*)(smem + 24960);
    short* sT2  = (short*)(smem + 25984);
    f32x2* sXP  = (f32x2*)(smem + 26368);   // [8][138]
    u32*  sA1   = (u32*)(smem + 35200);     // [8][32]
    u64*  sA2   = (u64*)(smem + 36224);     // [24][32]
    // post-L3 aliases:
    u64*  sW4   = (u64*)smem;               // [1536]
    u64*  sWf   = (u64*)(smem + 12288);     // [320]
    u64*  sFeat = (u64*)(smem + 24960);     // [4][32]
    short* sT4  = (short*)(smem + 25984);   // [128]
    float* sBf  = (float*)(smem + 26240);   // [10]
    u32*  sA3u  = (u32*)(smem + 26368);     // [24*64]
    u64*  sA3q  = (u64*)(smem + 26368);     // [24*32]

    int t = threadIdx.x;
    for (int i = t; i < 1536; i += 256) sB3[i] = b3i8[i];
    if (t < 32) {
        u32 n = t & 15;
        u32 e = 0;
#pragma unroll
        for (int j = 0; j < 4; ++j)
            e |= (((n >> j) & 1) ? 0x01u : 0xFFu) << (8 * j);
        sLUT4[t] = e;
    }
    if (t < 128) sC3[t] = (short)C3g[t];
    if (t < 64) sW2[t] = wt2v[t];
    if (t < 192) sT2[t] = (short)T2g[t];

    int co = t & 31, lane = t & 63;
    float4 wa = s1p[co * 3 + 0];
    float4 wb = s1p[co * 3 + 1];
    float wc = s1p[co * 3 + 2].x;
    double Tt = T1g[co];
    float Ttf = (float)Tt;
    // packed splat weights for the pk_fma chain
    f32x2 W0 = {wa.x, wa.x}, W1 = {wa.y, wa.y}, W2 = {wa.z, wa.z}, W3 = {wa.w, wa.w};
    f32x2 W4 = {wb.x, wb.x}, W5 = {wb.y, wb.y}, W6 = {wb.z, wb.z}, W7 = {wb.w, wb.w};
    f32x2 W8 = {wc, wc};

    int bh0 = blockIdx.x * RB;
#pragma unroll 1
    for (int ch = 0; ch < 3; ++ch) {
        __syncthreads();                       // protect sXP/sA1 reuse across chunks
        // packed staging: sXP[r][j] = (xpad[j], xpad[j+2]); xpad[c] = x[c-4] for c in [4,132)
        for (int i = t; i < 8 * 138; i += 256) {
            int r = i / 138, j = i - r * 138;
            const float* xrow = &x[(size_t)(bh0 + ch * 8 + r) * 128];
            float lo = (j >= 4 && j < 132) ? xrow[j - 4] : 0.f;
            float hi = (j >= 2 && j < 130) ? xrow[j - 2] : 0.f;
            sXP[r * 138 + j] = (f32x2){lo, hi};
        }
        __syncthreads();
        // ----- L1: packed f32 fast loop (v_pk_fma_f32); rare f64 fix-up hoisted out -----
        // Per-lane IEEE fma semantics identical to R10's scalar chain => same error
        // bound (<= ~1e-5) vs margin 5e-5; fix-up redoes the R5-verified f64 chain.
        {
            int rr = t >> 5;
            const f32x2* xp = &sXP[rr * 138];
            f32x2 P[9];
#pragma unroll
            for (int k = 0; k < 9; ++k) P[k] = xp[k];
            u32 myword = 0;
            u32 slowmask = 0;
#pragma unroll
            for (int wp = 0; wp < 32; ++wp) {
                f32x2 s = {0.f, 0.f};
                s = __builtin_elementwise_fma(W0, P[0], s);
                s = __builtin_elementwise_fma(W1, P[1], s);
                s = __builtin_elementwise_fma(W2, P[2], s);
                s = __builtin_elementwise_fma(W3, P[3], s);
                s = __builtin_elementwise_fma(W4, P[4], s);
                s = __builtin_elementwise_fma(W5, P[5], s);
                s = __builtin_elementwise_fma(W6, P[6], s);
                s = __builtin_elementwise_fma(W7, P[7], s);
                s = __builtin_elementwise_fma(W8, P[8], s);
                float m0 = fmaxf(s.x, s.y);
                bool pred = m0 >= Ttf;
                u64 mk = __ballot(pred);
                u32 hw = (lane < 32) ? (u32)mk : (u32)(mk >> 32);
                if ((lane & 31) == wp) myword = hw;
                if (__any(fabsf(m0 - Ttf) <= 5e-5f)) slowmask |= (1u << wp);
                // shift window to base 4(wp+1); loads reach xp[4*wp+12] <= xp[136]
#pragma unroll
                for (int k = 0; k < 5; ++k) P[k] = P[k + 4];
#pragma unroll
                for (int k = 5; k < 9; ++k) P[k] = xp[4 * wp + 4 + k];
            }
            // slowmask is wave-uniform (from __any) -> uniform loop, ballots safe.
            while (slowmask) {
                int wp = __builtin_ctz(slowmask);
                slowmask &= slowmask - 1;
                const f32x2* xw = &xp[4 * wp];
                // exact f64 recompute, same tap order as R5-verified kernel
                double d0 = 0.0, d1 = 0.0;
                f32x2 q0 = xw[0], q1 = xw[1], q2 = xw[2], q3 = xw[3], q4 = xw[4];
                f32x2 q5 = xw[5], q6 = xw[6], q7 = xw[7], q8 = xw[8];
                d0 = fma((double)wa.x, (double)q0.x, d0);  d1 = fma((double)wa.x, (double)q0.y, d1);
                d0 = fma((double)wa.y, (double)q1.x, d0);  d1 = fma((double)wa.y, (double)q1.y, d1);
                d0 = fma((double)wa.z, (double)q2.x, d0);  d1 = fma((double)wa.z, (double)q2.y, d1);
                d0 = fma((double)wa.w, (double)q3.x, d0);  d1 = fma((double)wa.w, (double)q3.y, d1);
                d0 = fma((double)wb.x, (double)q4.x, d0);  d1 = fma((double)wb.x, (double)q4.y, d1);
                d0 = fma((double)wb.y, (double)q5.x, d0);  d1 = fma((double)wb.y, (double)q5.y, d1);
                d0 = fma((double)wb.z, (double)q6.x, d0);  d1 = fma((double)wb.z, (double)q6.y, d1);
                d0 = fma((double)wb.w, (double)q7.x, d0);  d1 = fma((double)wb.w, (double)q7.y, d1);
                d0 = fma((double)wc,   (double)q8.x, d0);  d1 = fma((double)wc,   (double)q8.y, d1);
                bool pred = ((d0 > d1) ? d0 : d1) >= Tt;
                u64 mk = __ballot(pred);
                u32 hw = (lane < 32) ? (u32)mk : (u32)(mk >> 32);
                if ((lane & 31) == wp) myword = hw;
            }
            sA1[(((t >> 6) << 1) + (lane >> 5)) * 32 + (lane & 31)] = myword;
        }
        __syncthreads();
        // ----- L2 (verified body) -----
        {
            int r = t >> 5, wp = t & 31;
            u32 am = sA1[r * 32 + wp];
            u32 al = (wp > 0) ? sA1[r * 32 + wp - 1] : 0u;
            u32 ar = (wp < 31) ? sA1[r * 32 + wp + 1] : 0u;
            const short* Tp = &sT2[(wp == 0) ? 64 : ((wp == 31) ? 128 : 0)];
            u64 word2 = 0;
#pragma unroll
            for (int c = 0; c < 64; ++c) {
                uint4 w2v = sW2[c];
                int p = __popc(al ^ w2v.x) + __popc(am ^ w2v.y) + __popc(ar ^ w2v.z);
                word2 |= (u64)(p <= (int)Tp[c]) << c;
            }
            sA2[(ch * 8 + r) * 32 + wp] = word2;
        }
    }
    __syncthreads();

    // ----- L3 (verified MFMA body; nibble-LUT A-frag build; output to LDS sA3) -----
    int wq = t >> 6, m = lane & 31, half = lane >> 5;
    const u32* lp = sLUT4 + (half << 4);
    const int prTab[8] = {0, 1, 4, 5, 8, 9, 12, 13};
    for (int r6 = 0; r6 < 6; ++r6) {
        int row = wq * 6 + r6;
        u64 aw = sA2[row * 32 + m];
        u64 wm1 = (m > 0) ? sA2[row * 32 + m - 1] : 0ull;
        u64 wp1 = (m < 31) ? sA2[row * 32 + m + 1] : 0ull;

        v4i A[6];
#pragma unroll
        for (int kk = 0; kk < 6; ++kk) {
            const int kw = kk >> 1;
            u64 word = (kw == 0) ? wm1 : ((kw == 1) ? aw : wp1);
            bool valid = !((kw == 0 && m == 0) || (kw == 2 && m == 31));
            int ci0 = ((kk & 1) << 5) + (half << 4);
            u32 bits = (u32)(word >> ci0) & 0xFFFFu;
            u32 b0 = lp[bits & 15];
            u32 b1 = lp[(bits >> 4) & 15];
            u32 b2 = lp[(bits >> 8) & 15];
            u32 b3v = lp[bits >> 12];
            if (!valid) { b0 = 0; b1 = 0; b2 = 0; b3v = 0; }
            union { u32 d[4]; v4i v; } u;
            u.d[0] = b0; u.d[1] = b1; u.d[2] = b2; u.d[3] = b3v;
            A[kk] = u.v;
        }
        u32 outv = 0;
#pragma unroll
        for (int nt = 0; nt < 4; ++nt) {
            v16i acc;
#pragma unroll
            for (int i = 0; i < 16; ++i) acc[i] = 0;
#pragma unroll
            for (int kk = 0; kk < 6; ++kk) {
                int q = kk * 2 + half;
                union { uint4 u4; v4i v; } bu;
                bu.u4 = sB3[q * 128 + nt * 32 + m];
                acc = __builtin_amdgcn_mfma_i32_32x32x32_i8(A[kk], bu.v, acc, 0, 0, 0);
            }
            int tc = (int)sC3[nt * 32 + m];
#pragma unroll
            for (int rp = 0; rp < 8; ++rp) {
                int a0 = acc[2 * rp], a1 = acc[2 * rp + 1];
                int mx = (a0 > a1) ? a0 : a1;          // max+cmp replaces cmp+cmp+or
                bool c = mx >= tc;
                u64 mk = __ballot(c);
                int LA = (nt << 4) | prTab[rp];
                int LB = LA + 2;
                outv = (lane == LA) ? (u32)mk : outv;
                outv = (lane == LB) ? (u32)(mk >> 32) : outv;
            }
        }
        sA3u[row * 64 + ((lane & 15) << 2) + (lane >> 4)] = outv;
    }
    __syncthreads();     // all L3 sB3/sW2/sT2 reads done; sA3 complete

    // ----- stage L4/FC weights into dead regions -----
    for (int i = t; i < 1536; i += 256) sW4[i] = wt4[i];
    for (int i = t; i < 320; i += 256) sWf[i] = wtf[i];
    if (t < 128) sT4[t] = (short)T4g[t];
    if (t < 10) sBf[t] = bfg[t];
    __syncthreads();

    // ----- L4: wave = 1 local batch; lane = (cg = lane>>4 co-group, w = lane&15) -----
    {
        int bb = t >> 6;            // local batch 0..3
        int w = lane & 15;
        int cg = lane >> 4;         // co-group 0..3 (32 co each)
        u64 av[12];
#pragma unroll
        for (int h = 0; h < 6; ++h) {
            av[h * 2 + 0] = sA3q[(bb * 6 + h) * 32 + w * 2 + 0];
            av[h * 2 + 1] = sA3q[(bb * 6 + h) * 32 + w * 2 + 1];
        }
        u64 acc = 0;
#pragma unroll 4
        for (int c = 0; c < 32; ++c) {
            int cc = cg * 32 + c;
            const u64* wr = &sW4[cc * 12];
            int p = 0;
#pragma unroll
            for (int q = 0; q < 12; ++q) p += __popcll(av[q] ^ wr[q]);
            u64 mk = __ballot(p <= (int)sT4[cc]);
            u64 field = (mk >> (cg * 16)) & 0xFFFFull;
            acc |= field << ((c & 3) << 4);
            if ((c & 3) == 3) {
                if (w == (c >> 2)) sFeat[bb * 32 + cg * 8 + (c >> 2)] = acc;
                acc = 0;
            }
        }
    }
    __syncthreads();
    // ----- FC: 4 batches x 10 outputs -----
    if (t < 40) {
        int fb = t / 10, o = t % 10;
        int p = 0;
#pragma unroll
        for (int wi = 0; wi < 32; ++wi) p += __popcll(sFeat[fb * 32 + wi] ^ sWf[o * 32 + wi]);
        out[(size_t)(blockIdx.x * 4 + fb) * 10 + o] = __fadd_rn((float)(2048 - 2 * p), sBf[o]);
    }
}

// ---------------- launch ----------------
extern "C" void kernel_launch(void* const* d_in, const int* in_sizes, int n_in,
                              void* d_out, int out_size, void* d_ws, size_t ws_size,
                              hipStream_t stream) {
    const float* x  = (const float*)d_in[0];
    const float* w1 = (const float*)d_in[1];  const float* b1 = (const float*)d_in[2];
    const float* w2 = (const float*)d_in[3];  const float* b2 = (const float*)d_in[4];
    const float* w3 = (const float*)d_in[5];  const float* b3 = (const float*)d_in[6];
    const float* w4 = (const float*)d_in[7];  const float* b4 = (const float*)d_in[8];
    const float* g1 = (const float*)d_in[9];  const float* be1 = (const float*)d_in[10];
    const float* m1 = (const float*)d_in[11]; const float* v1 = (const float*)d_in[12];
    const float* g2 = (const float*)d_in[13]; const float* be2 = (const float*)d_in[14];
    const float* m2 = (const float*)d_in[15]; const float* v2 = (const float*)d_in[16];
    const float* g3 = (const float*)d_in[17]; const float* be3 = (const float*)d_in[18];
    const float* m3 = (const float*)d_in[19]; const float* v3 = (const float*)d_in[20];
    const float* g4 = (const float*)d_in[21]; const float* be4 = (const float*)d_in[22];
    const float* m4 = (const float*)d_in[23]; const float* v4 = (const float*)d_in[24];
    const float* wf = (const float*)d_in[25]; const float* bf = (const float*)d_in[26];
    float* out = (float*)d_out;

    char* ws = (char*)d_ws;
    uint4*  b3i8 = (uint4*) (ws + 0);         // 24576 B
    u64*    wt4  = (u64*)   (ws + 24576);     // 12288 B
    u64*    wtf  = (u64*)   (ws + 36864);     // 2560 B
    u32*    wt2w = (u32*)   (ws + 39424);     // 1024 B
    float*  s1f  = (float*) (ws + 40448);     // 1536 B
    double* T1   = (double*)(ws + 41984);     // 256 B (f64 thresholds)
    int*    T2   = (int*)   (ws + 42240);     // 768 B
    int*    C3   = (int*)   (ws + 43008);     // 512 B
    int*    T4   = (int*)   (ws + 43520);     // 512 B

    prep_all<<<18, 256, 0, stream>>>(w1, b1, w2, b2, w3, b3, w4, b4, wf,
                                     g1, be1, m1, v1, g2, be2, m2, v2,
                                     g3, be3, m3, v3, g4, be4, m4, v4,
                                     s1f, T1, wt2w, T2, b3i8, C3, wt4, T4, wtf);

    mega_kernel<<<(BATCH * 6) / RB, 256, 0, stream>>>(
        x, (const float4*)s1f, T1, (const uint4*)wt2w, T2, b3i8, C3,
        wt4, T4, wtf, bf, out);
}

// Round 12
// 237.253 us; speedup vs baseline: 1.1157x; 1.1157x over previous
//
#include <hip/hip_runtime.h>
#include <cstdint>
#include <cstddef>
#include <math.h>

#define BATCH 8192

typedef unsigned long long u64;
typedef uint32_t u32;
typedef int v4i __attribute__((ext_vector_type(4)));
typedef int v16i __attribute__((ext_vector_type(16)));

// ---- f64 BN semantics (matching the float64 numpy reference; R5-verified absmax=0) ----
__device__ __forceinline__ double bn_inv_d(float g, float v) {
    return (double)g * (1.0 / sqrt((double)v + 1e-5));
}
__device__ __forceinline__ double bn_shift_d(float be, float m, double iv) {
    return (double)be - (double)m * iv;
}
__device__ __forceinline__ double bn_eval_d(double conv, double B, double iv, double sh) {
    return (conv + B) * iv + sh;
}

// y(p) weakly decreasing => binary search == linear scan, bit-identical (R8/R9-verified).
template <typename F>
__device__ __forceinline__ int max_p_nonneg(F y, int maxp) {
    if (!(y(0) >= 0.0)) return -1;
    if (y(maxp) >= 0.0) return maxp;
    int lo = 0, hi = maxp;
    while (hi - lo > 1) {
        int mid = (lo + hi) >> 1;
        if (y(mid) >= 0.0) lo = mid; else hi = mid;
    }
    return lo;
}

// ---------------- one merged prep kernel (R9-verified) ----------------
__global__ __launch_bounds__(256) void prep_all(
    const float* w1, const float* b1, const float* w2, const float* b2,
    const float* w3, const float* b3, const float* w4, const float* b4,
    const float* wf,
    const float* g1, const float* be1, const float* m1, const float* v1,
    const float* g2, const float* be2, const float* m2, const float* v2,
    const float* g3, const float* be3, const float* m3, const float* v3,
    const float* g4, const float* be4, const float* m4, const float* v4,
    float* s1f, double* T1, u32* wt2w, int* T2,
    uint4* b3i8, int* C3, u64* wt4, int* T4, u64* wtf) {
    int t = blockIdx.x * 256 + threadIdx.x;

    if (t < 384) {
        int co = t / 12, k = t % 12;
        float val = 0.f;
        if (k < 9) {
            double iv = bn_inv_d(g1[co], v1[co]);
            float d = (iv < 0.0) ? -1.f : 1.f;
            val = ((w1[co * 9 + k] >= 0.f) ? 1.f : -1.f) * d;
        }
        s1f[t] = val;
    } else if (t < 416) {
        int co = t - 384;
        double iv = bn_inv_d(g1[co], v1[co]);
        double sh = bn_shift_d(be1[co], m1[co], iv);
        double B = (double)b1[co];
        bool flip = (iv < 0.0);
        double tt = -sh / iv - B;
        T1[co] = flip ? -tt : tt;
    } else if (t < 608) {
        int idx = t - 416;
        int co = idx / 3, kw = idx % 3;
        double iv = bn_inv_d(g2[co], v2[co]);
        bool flip = (iv < 0.0);
        u32 wb = 0;
        for (int ci = 0; ci < 32; ++ci)
            wb |= (u32)((w2[(co * 32 + ci) * 3 + kw] >= 0.f) != flip) << ci;
        wt2w[co * 4 + kw] = wb;
    } else if (t < 800) {
        int idx = t - 608;
        int co = idx & 63, cls = idx >> 6;
        double iv = bn_inv_d(g2[co], v2[co]);
        double sh = bn_shift_d(be2[co], m2[co], iv);
        double B = (double)b2[co];
        bool flip = (iv < 0.0);
        int spur = 0, nv = 3;
        if (cls == 1) { nv = 2; for (int ci = 0; ci < 32; ++ci) spur += (int)((w2[(co * 32 + ci) * 3 + 0] >= 0.f) != flip); }
        if (cls == 2) { nv = 2; for (int ci = 0; ci < 32; ++ci) spur += (int)((w2[(co * 32 + ci) * 3 + 2] >= 0.f) != flip); }
        int maxp = 32 * nv + spur;
        auto y = [&](int p) {
            int conv = flip ? (2 * (p - spur) - 32 * nv) : (32 * nv - 2 * (p - spur));
            return bn_eval_d((double)conv, B, iv, sh);
        };
        T2[cls * 64 + co] = max_p_nonneg(y, maxp);
    } else if (t < 2336) {
        int idx = t - 800;
        int q = idx >> 7, n = idx & 127;
        double iv = bn_inv_d(g3[n], v3[n]);
        bool flip = (iv < 0.0);
        int kw = q >> 2, ci0 = (q & 3) * 16;
        u32 wd[4] = {0, 0, 0, 0};
        for (int j = 0; j < 16; ++j) {
            int ci = ci0 + j;
            bool pos = (w3[(n * 64 + ci) * 3 + kw] >= 0.f) != flip;
            u32 byte = pos ? 0x01u : 0xFFu;
            wd[j >> 2] |= byte << (8 * (j & 3));
        }
        b3i8[idx] = make_uint4(wd[0], wd[1], wd[2], wd[3]);
    } else if (t < 2464) {
        int co = t - 2336;
        double iv = bn_inv_d(g3[co], v3[co]);
        double sh = bn_shift_d(be3[co], m3[co], iv);
        double B = (double)b3[co];
        auto y = [&](int v) { return bn_eval_d((double)v, B, iv, sh); };
        int C = 1000;
        if (iv >= 0.0) {
            if (y(192) >= 0.0) {
                if (y(-192) >= 0.0) C = -192;
                else {
                    int lo = 0, hi = 192;
                    while (hi - lo > 1) {
                        int mid = (lo + hi) >> 1;
                        if (y(-192 + 2 * mid) >= 0.0) hi = mid; else lo = mid;
                    }
                    C = -192 + 2 * hi;
                }
            }
        } else {
            if (y(192) >= 0.0) C = -192;
            else if (y(-192) >= 0.0) {
                int lo = 0, hi = 192;
                while (hi - lo > 1) {
                    int mid = (lo + hi) >> 1;
                    if (y(-192 + 2 * mid) >= 0.0) lo = mid; else hi = mid;
                }
                C = -(-192 + 2 * lo);
            }
        }
        C3[co] = C;
    } else if (t < 4000) {
        int idx = t - 2464;
        int j = idx & 1, ch = idx >> 1;
        int co = ch / 6, h = ch % 6;
        double iv = bn_inv_d(g4[co], v4[co]);
        bool flip = (iv < 0.0);
        u64 wb = 0;
        for (int cb = 0; cb < 64; ++cb) {
            int ci = j * 64 + cb;
            wb |= (u64)((w4[(co * 128 + ci) * 6 + h] >= 0.f) != flip) << cb;
        }
        wt4[idx] = wb;
    } else if (t < 4128) {
        int co = t - 4000;
        double iv = bn_inv_d(g4[co], v4[co]);
        double sh = bn_shift_d(be4[co], m4[co], iv);
        double B = (double)b4[co];
        bool flip = (iv < 0.0);
        auto y = [&](int p) {
            int conv = flip ? (2 * p - 768) : (768 - 2 * p);
            return bn_eval_d((double)conv, B, iv, sh);
        };
        T4[co] = max_p_nonneg(y, 768);
    } else if (t < 4448) {
        int idx = t - 4128;
        int o = idx / 32, wi = idx % 32;
        u64 wb = 0;
        for (int fb = 0; fb < 64; ++fb)
            wb |= (u64)(wf[o * 2048 + wi * 64 + fb] >= 0.f) << fb;
        wtf[idx] = wb;
    }
}

// ---------------- fully-fused L1..L4+FC (R10-verified best: mega 139us, bench 237.5us) ----------------
// LDS staging of B3/W4/Wf is LOAD-BEARING (R8: un-staging -> 557MB HBM fetch, 285us).
// 38656 B -> 3 blocks/CU under the 128KiB co-residency pool; VALU-bound at ~90%.
// R11 falsified pk_fma L1: packed window doubles LDS traffic and dropped occupancy.
#define RB 24
__global__ __launch_bounds__(256, 4) void mega_kernel(
    const float* __restrict__ x, const float4* __restrict__ s1p, const double* __restrict__ T1g,
    const uint4* __restrict__ wt2v, const int* __restrict__ T2g,
    const uint4* __restrict__ b3i8, const int* __restrict__ C3g,
    const u64* __restrict__ wt4, const int* __restrict__ T4g,
    const u64* __restrict__ wtf, const float* __restrict__ bfg,
    float* __restrict__ out) {
    __shared__ __attribute__((aligned(16))) char smem[38656];
    uint4* sB3  = (uint4*)smem;
    u32*  sLUT4 = (u32*)(smem + 24576);     // [2][16]
    short* sC3  = (short*)(smem + 24704);
    uint4* sW2  = (uint4*)(smem + 24960);
    short* sT2  = (short*)(smem + 25984);
    float* sX   = (float*)(smem + 26368);   // [8][140]
    u32*  sA1   = (u32*)(smem + 30848);     // [8][32]
    u64*  sA2   = (u64*)(smem + 32512);     // [24][32]
    // post-L3 aliases:
    u64*  sW4   = (u64*)smem;               // [1536]
    u64*  sWf   = (u64*)(smem + 12288);     // [320]
    u64*  sFeat = (u64*)(smem + 24960);     // [4][32]
    short* sT4  = (short*)(smem + 25984);   // [128]
    float* sBf  = (float*)(smem + 26240);   // [10]
    u32*  sA3u  = (u32*)(smem + 26368);     // [24*64]
    u64*  sA3q  = (u64*)(smem + 26368);     // [24*32]

    int t = threadIdx.x;
    for (int i = t; i < 1536; i += 256) sB3[i] = b3i8[i];
    if (t < 32) {
        u32 n = t & 15;
        u32 e = 0;
#pragma unroll
        for (int j = 0; j < 4; ++j)
            e |= (((n >> j) & 1) ? 0x01u : 0xFFu) << (8 * j);
        sLUT4[t] = e;
    }
    if (t < 128) sC3[t] = (short)C3g[t];
    if (t < 64) sW2[t] = wt2v[t];
    if (t < 192) sT2[t] = (short)T2g[t];

    int co = t & 31, lane = t & 63;
    float4 wa = s1p[co * 3 + 0];
    float4 wb = s1p[co * 3 + 1];
    float wc = s1p[co * 3 + 2].x;
    double Tt = T1g[co];
    float Ttf = (float)Tt;

    int bh0 = blockIdx.x * RB;
#pragma unroll 1
    for (int ch = 0; ch < 3; ++ch) {
        __syncthreads();                       // protect sX/sA1 reuse across chunks
        for (int i = t; i < 280; i += 256) {
            int r = i / 35, c = i - r * 35;
            float4 v = make_float4(0.f, 0.f, 0.f, 0.f);
            if (c >= 1 && c <= 32)
                v = *(const float4*)&x[(size_t)(bh0 + ch * 8 + r) * 128 + (c * 4 - 4)];
            *(float4*)&sX[r * 140 + c * 4] = v;
        }
        __syncthreads();
        // ----- L1: f32 fast loop; rare f64 fix-up hoisted out (single code copy) -----
        {
            int rr = t >> 5;
            const float* xr = &sX[rr * 140];
            float4 A0 = *(const float4*)&xr[0];
            float4 A1 = *(const float4*)&xr[4];
            float4 A2 = *(const float4*)&xr[8];
            u32 myword = 0;
            u32 slowmask = 0;
#pragma unroll
            for (int wp = 0; wp < 32; ++wp) {
                float s0 = 0.f, s1 = 0.f;
                s0 = fmaf(wa.x, A0.x, s0);  s1 = fmaf(wa.x, A0.z, s1);
                s0 = fmaf(wa.y, A0.y, s0);  s1 = fmaf(wa.y, A0.w, s1);
                s0 = fmaf(wa.z, A0.z, s0);  s1 = fmaf(wa.z, A1.x, s1);
                s0 = fmaf(wa.w, A0.w, s0);  s1 = fmaf(wa.w, A1.y, s1);
                s0 = fmaf(wb.x, A1.x, s0);  s1 = fmaf(wb.x, A1.z, s1);
                s0 = fmaf(wb.y, A1.y, s0);  s1 = fmaf(wb.y, A1.w, s1);
                s0 = fmaf(wb.z, A1.z, s0);  s1 = fmaf(wb.z, A2.x, s1);
                s0 = fmaf(wb.w, A1.w, s0);  s1 = fmaf(wb.w, A2.y, s1);
                s0 = fmaf(wc,   A2.x, s0);  s1 = fmaf(wc,   A2.z, s1);
                float m0 = fmaxf(s0, s1);
                bool pred = m0 >= Ttf;
                u64 mk = __ballot(pred);
                u32 hw = (lane < 32) ? (u32)mk : (u32)(mk >> 32);
                if ((lane & 31) == wp) myword = hw;
                if (__any(fabsf(m0 - Ttf) <= 5e-5f)) slowmask |= (1u << wp);
                A0 = A1; A1 = A2;
                A2 = *(const float4*)&xr[4 * wp + 12];   // wp=31 -> [136..139], in-bounds
            }
            // slowmask is wave-uniform (from __any) -> uniform loop, ballots safe.
            while (slowmask) {
                int wp = __builtin_ctz(slowmask);
                slowmask &= slowmask - 1;
                const float* xw = &xr[4 * wp];
                double d0 = 0.0, d1 = 0.0;
                d0 = fma((double)wa.x, (double)xw[0], d0);  d1 = fma((double)wa.x, (double)xw[2],  d1);
                d0 = fma((double)wa.y, (double)xw[1], d0);  d1 = fma((double)wa.y, (double)xw[3],  d1);
                d0 = fma((double)wa.z, (double)xw[2], d0);  d1 = fma((double)wa.z, (double)xw[4],  d1);
                d0 = fma((double)wa.w, (double)xw[3], d0);  d1 = fma((double)wa.w, (double)xw[5],  d1);
                d0 = fma((double)wb.x, (double)xw[4], d0);  d1 = fma((double)wb.x, (double)xw[6],  d1);
                d0 = fma((double)wb.y, (double)xw[5], d0);  d1 = fma((double)wb.y, (double)xw[7],  d1);
                d0 = fma((double)wb.z, (double)xw[6], d0);  d1 = fma((double)wb.z, (double)xw[8],  d1);
                d0 = fma((double)wb.w, (double)xw[7], d0);  d1 = fma((double)wb.w, (double)xw[9],  d1);
                d0 = fma((double)wc,   (double)xw[8], d0);  d1 = fma((double)wc,   (double)xw[10], d1);
                bool pred = ((d0 > d1) ? d0 : d1) >= Tt;
                u64 mk = __ballot(pred);
                u32 hw = (lane < 32) ? (u32)mk : (u32)(mk >> 32);
                if ((lane & 31) == wp) myword = hw;
            }
            sA1[(((t >> 6) << 1) + (lane >> 5)) * 32 + (lane & 31)] = myword;
        }
        __syncthreads();
        // ----- L2 (verified body) -----
        {
            int r = t >> 5, wp = t & 31;
            u32 am = sA1[r * 32 + wp];
            u32 al = (wp > 0) ? sA1[r * 32 + wp - 1] : 0u;
            u32 ar = (wp < 31) ? sA1[r * 32 + wp + 1] : 0u;
            const short* Tp = &sT2[(wp == 0) ? 64 : ((wp == 31) ? 128 : 0)];
            u64 word2 = 0;
#pragma unroll
            for (int c = 0; c < 64; ++c) {
                uint4 w2v = sW2[c];
                int p = __popc(al ^ w2v.x) + __popc(am ^ w2v.y) + __popc(ar ^ w2v.z);
                word2 |= (u64)(p <= (int)Tp[c]) << c;
            }
            sA2[(ch * 8 + r) * 32 + wp] = word2;
        }
    }
    __syncthreads();

    // ----- L3 (verified MFMA body; nibble-LUT A-frag build; output to LDS sA3) -----
    int wq = t >> 6, m = lane & 31, half = lane >> 5;
    const u32* lp = sLUT4 + (half << 4);
    const int prTab[8] = {0, 1, 4, 5, 8, 9, 12, 13};
    for (int r6 = 0; r6 < 6; ++r6) {
        int row = wq * 6 + r6;
        u64 aw = sA2[row * 32 + m];
        u64 wm1 = (m > 0) ? sA2[row * 32 + m - 1] : 0ull;
        u64 wp1 = (m < 31) ? sA2[row * 32 + m + 1] : 0ull;

        v4i A[6];
#pragma unroll
        for (int kk = 0; kk < 6; ++kk) {
            const int kw = kk >> 1;
            u64 word = (kw == 0) ? wm1 : ((kw == 1) ? aw : wp1);
            bool valid = !((kw == 0 && m == 0) || (kw == 2 && m == 31));
            int ci0 = ((kk & 1) << 5) + (half << 4);
            u32 bits = (u32)(word >> ci0) & 0xFFFFu;
            u32 b0 = lp[bits & 15];
            u32 b1 = lp[(bits >> 4) & 15];
            u32 b2 = lp[(bits >> 8) & 15];
            u32 b3v = lp[bits >> 12];
            if (!valid) { b0 = 0; b1 = 0; b2 = 0; b3v = 0; }
            union { u32 d[4]; v4i v; } u;
            u.d[0] = b0; u.d[1] = b1; u.d[2] = b2; u.d[3] = b3v;
            A[kk] = u.v;
        }
        u32 outv = 0;
#pragma unroll
        for (int nt = 0; nt < 4; ++nt) {
            v16i acc;
#pragma unroll
            for (int i = 0; i < 16; ++i) acc[i] = 0;
#pragma unroll
            for (int kk = 0; kk < 6; ++kk) {
                int q = kk * 2 + half;
                union { uint4 u4; v4i v; } bu;
                bu.u4 = sB3[q * 128 + nt * 32 + m];
                acc = __builtin_amdgcn_mfma_i32_32x32x32_i8(A[kk], bu.v, acc, 0, 0, 0);
            }
            int tc = (int)sC3[nt * 32 + m];
#pragma unroll
            for (int rp = 0; rp < 8; ++rp) {
                int a0 = acc[2 * rp], a1 = acc[2 * rp + 1];
                int mx = (a0 > a1) ? a0 : a1;
                bool c = mx >= tc;
                u64 mk = __ballot(c);
                int LA = (nt << 4) | prTab[rp];
                int LB = LA + 2;
                outv = (lane == LA) ? (u32)mk : outv;
                outv = (lane == LB) ? (u32)(mk >> 32) : outv;
            }
        }
        sA3u[row * 64 + ((lane & 15) << 2) + (lane >> 4)] = outv;
    }
    __syncthreads();     // all L3 sB3/sW2/sT2 reads done; sA3 complete

    // ----- stage L4/FC weights into dead regions -----
    for (int i = t; i < 1536; i += 256) sW4[i] = wt4[i];
    for (int i = t; i < 320; i += 256) sWf[i] = wtf[i];
    if (t < 128) sT4[t] = (short)T4g[t];
    if (t < 10) sBf[t] = bfg[t];
    __syncthreads();

    // ----- L4: wave = 1 local batch; lane = (cg = lane>>4 co-group, w = lane&15) -----
    {
        int bb = t >> 6;            // local batch 0..3
        int w = lane & 15;
        int cg = lane >> 4;         // co-group 0..3 (32 co each)
        u64 av[12];
#pragma unroll
        for (int h = 0; h < 6; ++h) {
            av[h * 2 + 0] = sA3q[(bb * 6 + h) * 32 + w * 2 + 0];
            av[h * 2 + 1] = sA3q[(bb * 6 + h) * 32 + w * 2 + 1];
        }
        u64 acc = 0;
#pragma unroll 4
        for (int c = 0; c < 32; ++c) {
            int cc = cg * 32 + c;
            const u64* wr = &sW4[cc * 12];
            int p = 0;
#pragma unroll
            for (int q = 0; q < 12; ++q) p += __popcll(av[q] ^ wr[q]);
            u64 mk = __ballot(p <= (int)sT4[cc]);
            u64 field = (mk >> (cg * 16)) & 0xFFFFull;
            acc |= field << ((c & 3) << 4);
            if ((c & 3) == 3) {
                if (w == (c >> 2)) sFeat[bb * 32 + cg * 8 + (c >> 2)] = acc;
                acc = 0;
            }
        }
    }
    __syncthreads();
    // ----- FC: 4 batches x 10 outputs -----
    if (t < 40) {
        int fb = t / 10, o = t % 10;
        int p = 0;
#pragma unroll
        for (int wi = 0; wi < 32; ++wi) p += __popcll(sFeat[fb * 32 + wi] ^ sWf[o * 32 + wi]);
        out[(size_t)(blockIdx.x * 4 + fb) * 10 + o] = __fadd_rn((float)(2048 - 2 * p), sBf[o]);
    }
}

// ---------------- launch ----------------
extern "C" void kernel_launch(void* const* d_in, const int* in_sizes, int n_in,
                              void* d_out, int out_size, void* d_ws, size_t ws_size,
                              hipStream_t stream) {
    const float* x  = (const float*)d_in[0];
    const float* w1 = (const float*)d_in[1];  const float* b1 = (const float*)d_in[2];
    const float* w2 = (const float*)d_in[3];  const float* b2 = (const float*)d_in[4];
    const float* w3 = (const float*)d_in[5];  const float* b3 = (const float*)d_in[6];
    const float* w4 = (const float*)d_in[7];  const float* b4 = (const float*)d_in[8];
    const float* g1 = (const float*)d_in[9];  const float* be1 = (const float*)d_in[10];
    const float* m1 = (const float*)d_in[11]; const float* v1 = (const float*)d_in[12];
    const float* g2 = (const float*)d_in[13]; const float* be2 = (const float*)d_in[14];
    const float* m2 = (const float*)d_in[15]; const float* v2 = (const float*)d_in[16];
    const float* g3 = (const float*)d_in[17]; const float* be3 = (const float*)d_in[18];
    const float* m3 = (const float*)d_in[19]; const float* v3 = (const float*)d_in[20];
    const float* g4 = (const float*)d_in[21]; const float* be4 = (const float*)d_in[22];
    const float* m4 = (const float*)d_in[23]; const float* v4 = (const float*)d_in[24];
    const float* wf = (const float*)d_in[25]; const float* bf = (const float*)d_in[26];
    float* out = (float*)d_out;

    char* ws = (char*)d_ws;
    uint4*  b3i8 = (uint4*) (ws + 0);         // 24576 B
    u64*    wt4  = (u64*)   (ws + 24576);     // 12288 B
    u64*    wtf  = (u64*)   (ws + 36864);     // 2560 B
    u32*    wt2w = (u32*)   (ws + 39424);     // 1024 B
    float*  s1f  = (float*) (ws + 40448);     // 1536 B
    double* T1   = (double*)(ws + 41984);     // 256 B (f64 thresholds)
    int*    T2   = (int*)   (ws + 42240);     // 768 B
    int*    C3   = (int*)   (ws + 43008);     // 512 B
    int*    T4   = (int*)   (ws + 43520);     // 512 B

    prep_all<<<18, 256, 0, stream>>>(w1, b1, w2, b2, w3, b3, w4, b4, wf,
                                     g1, be1, m1, v1, g2, be2, m2, v2,
                                     g3, be3, m3, v3, g4, be4, m4, v4,
                                     s1f, T1, wt2w, T2, b3i8, C3, wt4, T4, wtf);

    mega_kernel<<<(BATCH * 6) / RB, 256, 0, stream>>>(
        x, (const float4*)s1f, T1, (const uint4*)wt2w, T2, b3i8, C3,
        wt4, T4, wtf, bf, out);
}